// Round 1
// baseline (465.291 us; speedup 1.0000x reference)
//
#include <hip/hip_runtime.h>
#include <math.h>

// ---------------------------------------------------------------------------
// SO8T rotation gate: y[b,t,n,:] = x[b,t,n,:] @ R[n],  R[n] = scale-square
// Taylor expm of A[n] = theta[n] - theta[n]^T, faithful to reference
// (per-block s for scaling, global max_s squaring count, EPS spots included).
//
// v2 changes vs previous session's kernel:
//  - smax_kernel removed: ceil/log2/sqrt are monotone, so
//    max_s = clamp(ceil(log2(sqrt(max_b norm2_b)+EPS))). Each expm workgroup
//    redundantly computes the global max from L2-hot theta (~2-3 us chip-wide)
//    instead of one single-CU latency-bound kernel + extra launch gap.
//  - apply_kernel: perfect per-instruction coalescing. Each lane loads ONE
//    contiguous float4 (1024B fully-used per wave instruction, vs the old
//    stride-32B pattern that touched 2048B per instruction at 50% line use).
//    Lane pairs exchange block halves via 4x __shfl_xor (VALU, no LDS).
//    R fragment per lane: 32 floats (rows permuted by half so no selects).
// ---------------------------------------------------------------------------

#define MAX_ITER 12
#define EPS 1e-7f
#define SQ_CAP 8
#define ROWS_PER_BLOCK 32

// Kernel 1: per-block expm. One workgroup (1 wave, 64 lanes) per 8x8 block;
// lane (i,j) owns entry [i][j]. Phase A computes the global squaring count
// redundantly per workgroup.
__global__ __launch_bounds__(64) void expm_kernel(const float* __restrict__ theta,
                                                  float* __restrict__ Rbuf,
                                                  int num_blocks) {
    const int n = blockIdx.x;
    const int lane = threadIdx.x;
    const int i = lane >> 3, j = lane & 7;

    // ---- Phase A: global max norm^2 over all blocks (redundant per wg).
    // Each lane scans blocks lane, lane+64, ... holding one 8x8 block fully
    // in registers (static indexing only -> stays in VGPRs).
    float maxn2 = 0.0f;
    for (int b = lane; b < num_blocks; b += 64) {
        const float4* tp = (const float4*)(theta + (size_t)b * 64);
        float t[64];
        #pragma unroll
        for (int q = 0; q < 16; ++q) {
            float4 v = tp[q];
            t[q * 4 + 0] = v.x; t[q * 4 + 1] = v.y;
            t[q * 4 + 2] = v.z; t[q * 4 + 3] = v.w;
        }
        float n2b = 0.0f;
        #pragma unroll
        for (int ii = 0; ii < 8; ++ii)
            #pragma unroll
            for (int jj = 0; jj < 8; ++jj) {
                float d = t[ii * 8 + jj] - t[jj * 8 + ii];
                n2b = fmaf(d, d, n2b);
            }
        maxn2 = fmaxf(maxn2, n2b);
    }
    #pragma unroll
    for (int off = 32; off >= 1; off >>= 1)
        maxn2 = fmaxf(maxn2, __shfl_xor(maxn2, off, 64));
    // max_s = clamp(ceil(log2(max_norm + EPS)), 0) — monotone, so max
    // commutes through ceil/log2/sqrt. Matches reference per-block s + max.
    float smax = ceilf(log2f(sqrtf(maxn2) + EPS));
    if (smax < 0.0f) smax = 0.0f;
    int ms = (int)smax;
    if (ms > SQ_CAP) ms = SQ_CAP;

    // ---- Phase B: own block. Coalesced load + in-wave transpose.
    float e = theta[(size_t)n * 64 + lane];
    float eT = __shfl(e, ((lane & 7) << 3) | (lane >> 3), 64);
    float a = e - eT;

    // Frobenius norm^2 over the 64 entries (wave reduction).
    float n2 = a * a;
    #pragma unroll
    for (int off = 32; off >= 1; off >>= 1) n2 += __shfl_xor(n2, off, 64);

    float norm = sqrtf(n2);
    float s = ceilf(log2f(norm + EPS));
    if (s < 0.0f) s = 0.0f;
    float scale = exp2f(s);
    float as = a / (scale + EPS);

    __shared__ float As[64];
    __shared__ float Ap[64];
    As[lane] = as;

    float R = (i == j) ? 1.0f : 0.0f;
    float Apow = as;
    float fact = 1.0f;
    __syncthreads();

    for (int it = 1; it <= MAX_ITER; ++it) {
        fact *= (float)it;
        R += Apow / fact;
        if (it < MAX_ITER) {
            Ap[lane] = Apow;
            __syncthreads();
            float t = 0.0f;
            #pragma unroll
            for (int k = 0; k < 8; ++k) t = fmaf(Ap[i * 8 + k], As[k * 8 + j], t);
            __syncthreads();
            Apow = t;
        }
    }

    for (int k2 = 0; k2 < ms; ++k2) {
        Ap[lane] = R;
        __syncthreads();
        float t = 0.0f;
        #pragma unroll
        for (int k = 0; k < 8; ++k) t = fmaf(Ap[i * 8 + k], Ap[k * 8 + j], t);
        __syncthreads();
        R = t;
    }
    Rbuf[(size_t)n * 64 + lane] = R;
}

// Kernel 2: streaming apply, perfect coalescing.
// float4 index within row: f = blockIdx.y*256 + tid. Block n = f>>1,
// half h = f&1 (this lane computes outputs o = h*4..h*4+3 of block n).
// xv[0..3] = own float4 (elements h*4+k), xv[4..7] = partner half via shfl_xor(1)
// (elements (1-h)*4+k). R rows are loaded in that same permuted order, so the
// inner product is a straight 8-step FMA with static indexing.
__global__ __launch_bounds__(256) void apply_kernel(const float* __restrict__ x,
                                                    const float* __restrict__ Rbuf,
                                                    float* __restrict__ y,
                                                    int D) {
    const int tid = threadIdx.x;
    const int f = blockIdx.y * 256 + tid;   // float4 index within a row
    const int n = f >> 1;                   // 8x8 block index
    const int h = f & 1;                    // which half of the block
    const long r0 = (long)blockIdx.x * ROWS_PER_BLOCK;

    // 32 R values for this lane: R[n][e(k)][h*4 + q], k=0..7, q=0..3.
    float4 rr[8];
    const float* Rb = Rbuf + (size_t)n * 64 + h * 4;
    #pragma unroll
    for (int k = 0; k < 8; ++k) {
        int e = (k < 4) ? (h * 4 + k) : ((1 - h) * 4 + (k - 4));
        rr[k] = *(const float4*)(Rb + e * 8);
    }

    const int d4 = D >> 2;
    const float4* xp = (const float4*)(x + r0 * D) + f;
    float4*       yp = (float4*)(y + r0 * D) + f;

    #pragma unroll 4
    for (int k = 0; k < ROWS_PER_BLOCK; ++k) {
        float4 v = *xp;
        float4 u;
        u.x = __shfl_xor(v.x, 1, 64);
        u.y = __shfl_xor(v.y, 1, 64);
        u.z = __shfl_xor(v.z, 1, 64);
        u.w = __shfl_xor(v.w, 1, 64);
        float xv[8] = {v.x, v.y, v.z, v.w, u.x, u.y, u.z, u.w};
        float4 acc;
        acc.x = xv[0] * rr[0].x;
        acc.y = xv[0] * rr[0].y;
        acc.z = xv[0] * rr[0].z;
        acc.w = xv[0] * rr[0].w;
        #pragma unroll
        for (int k2 = 1; k2 < 8; ++k2) {
            acc.x = fmaf(xv[k2], rr[k2].x, acc.x);
            acc.y = fmaf(xv[k2], rr[k2].y, acc.y);
            acc.z = fmaf(xv[k2], rr[k2].z, acc.z);
            acc.w = fmaf(xv[k2], rr[k2].w, acc.w);
        }
        *yp = acc;
        xp += d4;
        yp += d4;
    }
}

extern "C" void kernel_launch(void* const* d_in, const int* in_sizes, int n_in,
                              void* d_out, int out_size, void* d_ws, size_t ws_size,
                              hipStream_t stream) {
    const float* x     = (const float*)d_in[0];
    const float* theta = (const float*)d_in[1];
    float* y = (float*)d_out;

    const int tsize = in_sizes[1];              // element count of theta
    const int num_blocks = tsize / 64;          // 512
    const int D = num_blocks * 8;               // 4096
    const long rows = (long)in_sizes[0] / D;    // B*T = 16384

    float* Rbuf = (float*)d_ws;

    expm_kernel<<<num_blocks, 64, 0, stream>>>(theta, Rbuf, num_blocks);

    // Each workgroup covers 256 float4 = 1024 floats of a row.
    dim3 grid((unsigned)(rows / ROWS_PER_BLOCK), (unsigned)(D / 1024));
    apply_kernel<<<grid, 256, 0, stream>>>(x, Rbuf, y, D);
}